// Round 14
// baseline (291.726 us; speedup 1.0000x reference)
//
#include <hip/hip_runtime.h>

#define NN 65536
#define NE 1048576
#define NB 64
#define HD 128
#define HD2 256
#define NHEAD 4
#define NPG 1024
#define BEPS 1e-5f
#define BM 64
#define ESTRIDE 20480   // per-graph edge bucket stride (mean 16384, +32 sigma)

typedef short bf16x8s __attribute__((ext_vector_type(8)));
typedef float f32x4 __attribute__((ext_vector_type(4)));
#define MFMA16(a,b,c) __builtin_amdgcn_mfma_f32_16x16x32_bf16(a,b,c,0,0,0)

__device__ __forceinline__ unsigned short f2bf(float f) {
    union { float f; unsigned int u; } x{f};
    unsigned int r = x.u + 0x7FFFu + ((x.u >> 16) & 1u);
    return (unsigned short)(r >> 16);
}
__device__ __forceinline__ float b2f(unsigned short s) {
    union { unsigned int u; float f; } x{((unsigned int)s) << 16};
    return x.f;
}

// ---------------- prep pass 1: bucket edges by graph + pool partials ----------------
__global__ __launch_bounds__(1024) void k_prep_pool(const int* __restrict__ src, const int* __restrict__ dst,
                                                    int* __restrict__ gcurD, int* __restrict__ gcurS,
                                                    unsigned int* __restrict__ dbuck, unsigned short* __restrict__ sbuck,
                                                    const float* __restrict__ h,
                                                    float* __restrict__ psum, float* __restrict__ psq) {
    const int t = threadIdx.x;
    if (blockIdx.x < 64) {
        __shared__ int cntD[64], cntS[64], baseD[64], baseS[64];
        if (t < 64) { cntD[t] = 0; cntS[t] = 0; }
        __syncthreads();
        const int e0 = blockIdx.x * 16384;
        int sv[16], dv[16];
        #pragma unroll
        for (int j = 0; j < 16; ++j) {
            int e = e0 + j * 1024 + t;
            sv[j] = src[e]; dv[j] = dst[e];
            atomicAdd(&cntD[dv[j] >> 10], 1);
            atomicAdd(&cntS[sv[j] >> 10], 1);
        }
        __syncthreads();
        if (t < 64) baseD[t] = atomicAdd(&gcurD[t * 32], cntD[t]);
        else if (t < 128) baseS[t - 64] = atomicAdd(&gcurS[(t - 64) * 32], cntS[t - 64]);
        __syncthreads();
        if (t < 64) { cntD[t] = 0; cntS[t] = 0; }
        __syncthreads();
        #pragma unroll
        for (int j = 0; j < 16; ++j) {
            int gd = dv[j] >> 10;
            int slot = baseD[gd] + atomicAdd(&cntD[gd], 1);
            if (slot < ESTRIDE)
                dbuck[gd * ESTRIDE + slot] = (unsigned)(dv[j] & 1023) | ((unsigned)sv[j] << 10);
            int gs = sv[j] >> 10;
            int slot2 = baseS[gs] + atomicAdd(&cntS[gs], 1);
            if (slot2 < ESTRIDE)
                sbuck[gs * ESTRIDE + slot2] = (unsigned short)(sv[j] & 1023);
        }
    } else {
        __shared__ float ls[1024], lq[1024];
        const int bb = blockIdx.x - 64;     // 256 strips of 256 rows
        const int r0 = bb * 256;
        const int c = t & 127, strip8 = t >> 7;
        float s = 0.f, sq = 0.f;
        for (int i = 0; i < 32; ++i) {
            float v = h[(size_t)(r0 + strip8 * 32 + i) * HD + c];
            s += v; sq += v * v;
        }
        ls[t] = s; lq[t] = sq;
        __syncthreads();
        if (t < 128) {
            float ss = 0.f, qq = 0.f;
            #pragma unroll
            for (int k = 0; k < 8; ++k) { ss += ls[t + k * 128]; qq += lq[t + k * 128]; }
            psum[bb * HD + t] = ss;
            psq[bb * HD + t]  = qq;
        }
    }
}

// ---------------- prep pass 2: per-graph CSR build (u16 elist) + degrees ----------------
__global__ __launch_bounds__(1024) void k_prep2(const int* __restrict__ gcurD, const int* __restrict__ gcurS,
                                                const unsigned int* __restrict__ dbuck,
                                                const unsigned short* __restrict__ sbuck,
                                                float* __restrict__ din_r, float* __restrict__ dout_r,
                                                int* __restrict__ beg, int* __restrict__ endv,
                                                unsigned short* __restrict__ elist) {
    __shared__ int hist[1024];
    __shared__ int pre[1024];
    const int t = threadIdx.x;
    const int b = blockIdx.x;
    if (b < 64) {
        const int g = b;
        const int n = min(gcurD[g * 32], ESTRIDE);
        const unsigned int* pd = dbuck + g * ESTRIDE;
        hist[t] = 0;
        __syncthreads();
        for (int i = t; i < n; i += 1024) atomicAdd(&hist[pd[i] & 1023], 1);
        __syncthreads();
        const int cnt = hist[t];
        din_r[g * 1024 + t] = rsqrtf((float)max(cnt, 1));
        int x = cnt; pre[t] = x;
        __syncthreads();
        #pragma unroll
        for (int off = 1; off < 1024; off <<= 1) {
            int v = (t >= off) ? pre[t - off] : 0;
            __syncthreads();
            x += v; pre[t] = x;
            __syncthreads();
        }
        const int excl = x - cnt;
        beg[g * 1024 + t]  = g * ESTRIDE + excl;
        endv[g * 1024 + t] = g * ESTRIDE + excl + cnt;
        __syncthreads();
        hist[t] = excl; pre[t] = 0;
        __syncthreads();
        for (int i = t; i < n; i += 1024) {
            unsigned int w = pd[i];
            int dl = w & 1023;
            int r = atomicAdd(&pre[dl], 1);
            elist[g * ESTRIDE + hist[dl] + r] = (unsigned short)(w >> 10);   // src fits u16
        }
    } else {
        const int g = b - 64;
        const int m = min(gcurS[g * 32], ESTRIDE);
        const unsigned short* ps = sbuck + g * ESTRIDE;
        hist[t] = 0;
        __syncthreads();
        for (int i = t; i < m; i += 1024) atomicAdd(&hist[ps[i]], 1);
        __syncthreads();
        dout_r[g * 1024 + t] = rsqrtf((float)max(hist[t], 1));
    }
}

// ---------------- fused: pack xr = bf16(h*dout_r)  |  sd[d] = sum dout_r[src] ----------------
__global__ __launch_bounds__(256) void k_sdpack(const float* __restrict__ x, const float* __restrict__ dout_r,
                                                unsigned short* __restrict__ xr,
                                                const int* __restrict__ beg, const int* __restrict__ endv,
                                                const unsigned short* __restrict__ elist,
                                                float* __restrict__ sd) {
    if (blockIdx.x < 4096) {
        int idx = blockIdx.x * 256 + threadIdx.x;     // N*16 threads, 8 elems each
        int node = idx >> 4;
        int c8 = (idx & 15) * 8;
        float dr = dout_r[node];
        float4 v0 = *(const float4*)(x + (size_t)node * HD + c8);
        float4 v1 = *(const float4*)(x + (size_t)node * HD + c8 + 4);
        union { uint4 v; unsigned short u[8]; } pk;
        pk.u[0] = f2bf(v0.x * dr); pk.u[1] = f2bf(v0.y * dr);
        pk.u[2] = f2bf(v0.z * dr); pk.u[3] = f2bf(v0.w * dr);
        pk.u[4] = f2bf(v1.x * dr); pk.u[5] = f2bf(v1.y * dr);
        pk.u[6] = f2bf(v1.z * dr); pk.u[7] = f2bf(v1.w * dr);
        *(uint4*)(xr + (size_t)node * HD + c8) = pk.v;
    } else {
        const int node = (blockIdx.x - 4096) * 256 + threadIdx.x;
        const int b0 = beg[node], e0 = endv[node];
        float s = 0.f;
        for (int i = b0; i < e0; ++i) s += dout_r[elist[i]];
        sd[node] = s;
    }
}

// ---------------- fused weight prep + pass-1 stats reduce + init_avg ----------------
__device__ __forceinline__ void dev_prepW(int idx, const float* __restrict__ W,
                                          unsigned short* __restrict__ frag, int O) {
    int l = idx & 63, tt = idx >> 6;
    int ot = O >> 4;
    int c = tt % ot, ks = tt / ot;
    int q = l >> 4, m = l & 15;
    const float* wp = W + (size_t)(ks * 32 + q * 8) * O + c * 16 + m;
    union { uint4 v; unsigned short u[8]; } pk;
    #pragma unroll
    for (int j = 0; j < 8; ++j) pk.u[j] = f2bf(wp[(size_t)j * O]);
    *(uint4*)(frag + (size_t)idx * 8) = pk.v;
}

__global__ __launch_bounds__(256) void k_wprep(const float* __restrict__ W1, const float* __restrict__ W2,
                                               const float* __restrict__ Wf1, const float* __restrict__ Wf2,
                                               const float* __restrict__ interf, const float* __restrict__ Wk,
                                               const float* __restrict__ Wq, const float* __restrict__ Wv,
                                               const float* __restrict__ Wc,
                                               unsigned short* __restrict__ W1f, unsigned short* __restrict__ W2f,
                                               unsigned short* __restrict__ Wf1f, unsigned short* __restrict__ Wf2f,
                                               float* __restrict__ watt, unsigned short* __restrict__ Uf,
                                               const float* __restrict__ psum, const float* __restrict__ psq,
                                               float* __restrict__ out_avg,
                                               float* __restrict__ colsum, float* __restrict__ colsq) {
    const int b = blockIdx.x, t = threadIdx.x;
    if (b < 8)        dev_prepW(b * 256 + t, W1, W1f, 128);
    else if (b < 16)  dev_prepW((b - 8) * 256 + t, W2, W2f, 128);
    else if (b < 32)  dev_prepW((b - 16) * 256 + t, Wf1, Wf1f, 256);
    else if (b < 48)  dev_prepW((b - 32) * 256 + t, Wf2, Wf2f, 128);
    else if (b < 304) {
        int hb = b - 48;                 // h*64+g
        int hh = hb >> 6, g = hb & 63;
        __shared__ float f[HD];
        __shared__ float kv[HD];
        if (t < HD) f[t] = interf[g * HD + t];
        __syncthreads();
        if (t < HD) {
            const float* Wkh = Wk + (size_t)hh * HD * HD;
            float s = 0.f;
            for (int d = 0; d < HD; ++d) s += f[d] * Wkh[(size_t)d * HD + t];
            kv[t] = s;
        }
        __syncthreads();
        if (t < HD) {
            const float* row = Wq + ((size_t)hh * HD + t) * HD;
            float s2 = 0.f;
            #pragma unroll 4
            for (int o = 0; o < HD; o += 4) {
                float4 w = *(const float4*)(row + o);
                s2 += w.x * kv[o] + w.y * kv[o + 1] + w.z * kv[o + 2] + w.w * kv[o + 3];
            }
            watt[hb * HD + t] = s2 * 0.027950849718747373f;   // 1/sqrt(1280)
        }
    } else if (b < 560) {
        int idx = (b - 304) * 256 + t;   // 65536 total
        int o = idx & 127;
        int d = (idx >> 7) & 127;
        int hh = idx >> 14;
        const float* wv = Wv + ((size_t)hh * HD + d) * HD;
        const float* wc = Wc + (size_t)(hh * HD) * HD + o;
        float s = 0.f;
        for (int m2 = 0; m2 < HD; ++m2) s += wv[m2] * wc[(size_t)m2 * HD];
        int ks = d >> 5, dd = d & 31, q = dd >> 3, j = dd & 7;
        int c = o >> 4, m = o & 15, l = q * 16 + m;
        Uf[(size_t)((((hh * 4 + ks) * 8 + c) * 64 + l) * 8 + j)] = f2bf(s);
    } else {
        // pass-1 BN stats + init mean pooling from non-atomic partials
        const int col = b - 560;         // 128 blocks, one column each
        __shared__ float ls[256], lq[256];
        ls[t] = psum[t * HD + col];
        lq[t] = psq[t * HD + col];
        __syncthreads();
        if (t < 64) {
            float a4 = ls[4 * t] + ls[4 * t + 1] + ls[4 * t + 2] + ls[4 * t + 3];
            out_avg[t * HD + col] = a4 * (1.0f / NPG);
            float b4 = lq[4 * t] + lq[4 * t + 1] + lq[4 * t + 2] + lq[4 * t + 3];
            float ts = a4, tq = b4;
            #pragma unroll
            for (int mk = 1; mk <= 32; mk <<= 1) {
                ts += __shfl_xor(ts, mk, 64);
                tq += __shfl_xor(tq, mk, 64);
            }
            if (t == 0) { colsum[col] = ts; colsq[col] = tq; }
        }
    }
}

// ---------------- CSR aggregation: wave per node, 16 lanes/row (uint4), 4 edge-groups x4 unroll ----------------
// agg_bn[d][c] = din[d] * ( sc[c]*sum(xr[s][c]) + sh[c]*sd[d] ),  xr = bf16(x*dout_r)
__global__ __launch_bounds__(256) void k_aggregate(const unsigned short* __restrict__ xr,
                                                   const float* __restrict__ din_r, const float* __restrict__ sd,
                                                   const float* __restrict__ colsum, const float* __restrict__ colsq,
                                                   const float* __restrict__ gma, const float* __restrict__ bta,
                                                   const int* __restrict__ beg, const int* __restrict__ endv,
                                                   const unsigned short* __restrict__ elist,
                                                   unsigned short* __restrict__ agg) {
    const int tid = threadIdx.x;
    const int node = blockIdx.x * 4 + (tid >> 6);
    const int lane = tid & 63;
    const int grp = lane >> 4;              // 4 edge groups
    const int gl = lane & 15;               // lane-in-group: covers cols gl*8..gl*8+7 (16B)
    const int c8 = gl * 8;
    const int b0 = beg[node], e0 = endv[node];
    float a[8] = {};
    int i = b0 + grp;
    for (; i + 12 < e0; i += 16) {          // 4 edges for this group in flight
        int s0 = elist[i], s1 = elist[i + 4], s2 = elist[i + 8], s3 = elist[i + 12];
        union { uint4 v; unsigned short u[8]; } r0, r1, r2, r3;
        r0.v = *(const uint4*)(xr + (size_t)s0 * HD + c8);
        r1.v = *(const uint4*)(xr + (size_t)s1 * HD + c8);
        r2.v = *(const uint4*)(xr + (size_t)s2 * HD + c8);
        r3.v = *(const uint4*)(xr + (size_t)s3 * HD + c8);
        #pragma unroll
        for (int j = 0; j < 8; ++j)
            a[j] += b2f(r0.u[j]) + b2f(r1.u[j]) + b2f(r2.u[j]) + b2f(r3.u[j]);
    }
    for (; i < e0; i += 4) {
        int s = elist[i];
        union { uint4 v; unsigned short u[8]; } r;
        r.v = *(const uint4*)(xr + (size_t)s * HD + c8);
        #pragma unroll
        for (int j = 0; j < 8; ++j) a[j] += b2f(r.u[j]);
    }
    #pragma unroll
    for (int j = 0; j < 8; ++j) {
        a[j] += __shfl_xor(a[j], 16, 64);
        a[j] += __shfl_xor(a[j], 32, 64);
    }
    if (grp == 0) {
        float dn = din_r[node], sv = sd[node];
        union { uint4 v; unsigned short u[8]; } o;
        #pragma unroll
        for (int j = 0; j < 8; ++j) {
            float mj = colsum[c8 + j] * (1.0f / NN);
            float rj = rsqrtf(colsq[c8 + j] * (1.0f / NN) - mj * mj + BEPS);
            float scj = rj * gma[c8 + j];
            float shj = bta[c8 + j] - mj * scj;
            o.u[j] = f2bf(dn * (a[j] * scj + shj * sv));
        }
        *(uint4*)(agg + (size_t)node * HD + c8) = o.v;
    }
}

// ---------------- gconv MFMA: out(bf16) = res + relu(agg @ W + b); fused scores / stats / xr write ----------------
template<bool SCORES, bool STATS, bool RES32, bool WXR>
__global__ __launch_bounds__(256) void k_gconv_mfma(const unsigned short* __restrict__ agg,
                                                    const unsigned short* __restrict__ Wfrag,
                                                    const float* __restrict__ bias,
                                                    const void* __restrict__ res, unsigned short* __restrict__ outp,
                                                    const float* __restrict__ watt, float* __restrict__ att,
                                                    float* __restrict__ part2s, float* __restrict__ part2q,
                                                    const float* __restrict__ dout_r, unsigned short* __restrict__ xrout) {
    __shared__ float credS[4 * HD];
    __shared__ float credQ[4 * HD];
    const int tid = threadIdx.x;
    const int w = tid >> 6, l = tid & 63, q = l >> 4, m = l & 15;
    const int node = blockIdx.x * BM + w * 16 + m;
    bf16x8s a[4];
    #pragma unroll
    for (int ks = 0; ks < 4; ++ks)
        a[ks] = *(const bf16x8s*)(agg + (size_t)node * HD + ks * 32 + q * 8);
    f32x4 acc[8] = {};
    #pragma unroll
    for (int ks = 0; ks < 4; ++ks) {
        #pragma unroll
        for (int c = 0; c < 8; ++c) {
            bf16x8s b = *(const bf16x8s*)(Wfrag + (size_t)((ks * 8 + c) * 64 + l) * 8);
            acc[c] = MFMA16(b, a[ks], acc[c]);
        }
    }
    float vals[8][4];
    float drv = WXR ? dout_r[node] : 0.f;
    #pragma unroll
    for (int c = 0; c < 8; ++c) {
        const int col = c * 16 + q * 4;
        float4 bv = *(const float4*)(bias + col);
        float rv[4];
        if (RES32) {
            float4 r4 = *(const float4*)((const float*)res + (size_t)node * HD + col);
            rv[0] = r4.x; rv[1] = r4.y; rv[2] = r4.z; rv[3] = r4.w;
        } else {
            ushort4 r4 = *(const ushort4*)((const unsigned short*)res + (size_t)node * HD + col);
            rv[0] = b2f(r4.x); rv[1] = b2f(r4.y); rv[2] = b2f(r4.z); rv[3] = b2f(r4.w);
        }
        vals[c][0] = rv[0] + fmaxf(acc[c][0] + bv.x, 0.f);
        vals[c][1] = rv[1] + fmaxf(acc[c][1] + bv.y, 0.f);
        vals[c][2] = rv[2] + fmaxf(acc[c][2] + bv.z, 0.f);
        vals[c][3] = rv[3] + fmaxf(acc[c][3] + bv.w, 0.f);
        ushort4 o;
        o.x = f2bf(vals[c][0]); o.y = f2bf(vals[c][1]);
        o.z = f2bf(vals[c][2]); o.w = f2bf(vals[c][3]);
        *(ushort4*)(outp + (size_t)node * HD + col) = o;
        if (WXR) {
            ushort4 o2;
            o2.x = f2bf(vals[c][0] * drv); o2.y = f2bf(vals[c][1] * drv);
            o2.z = f2bf(vals[c][2] * drv); o2.w = f2bf(vals[c][3] * drv);
            *(ushort4*)(xrout + (size_t)node * HD + col) = o2;
        }
    }
    if (SCORES) {
        const int g = node >> 10;
        #pragma unroll
        for (int hh = 0; hh < NHEAD; ++hh) {
            const float* wp = watt + ((size_t)(hh * NB + g)) * HD;
            float s = 0.f;
            #pragma unroll
            for (int c = 0; c < 8; ++c) {
                const int col = c * 16 + q * 4;
                float4 wv = *(const float4*)(wp + col);
                s += vals[c][0] * wv.x + vals[c][1] * wv.y + vals[c][2] * wv.z + vals[c][3] * wv.w;
            }
            s += __shfl_xor(s, 16, 64);
            s += __shfl_xor(s, 32, 64);
            if (q == 0) att[(size_t)hh * NN + node] = s;
        }
    }
    if (STATS) {
        #pragma unroll
        for (int c = 0; c < 8; ++c) {
            #pragma unroll
            for (int r = 0; r < 4; ++r) {
                float v = vals[c][r];
                float vq = v * v;
                #pragma unroll
                for (int mk = 1; mk <= 8; mk <<= 1) {
                    v  += __shfl_xor(v, mk, 64);
                    vq += __shfl_xor(vq, mk, 64);
                }
                if (m == 0) {
                    credS[w * HD + c * 16 + q * 4 + r] = v;
                    credQ[w * HD + c * 16 + q * 4 + r] = vq;
                }
            }
        }
        __syncthreads();
        if (tid < HD) {
            part2s[(size_t)blockIdx.x * HD + tid] =
                credS[tid] + credS[HD + tid] + credS[2 * HD + tid] + credS[3 * HD + tid];
            part2q[(size_t)blockIdx.x * HD + tid] =
                credQ[tid] + credQ[HD + tid] + credQ[2 * HD + tid] + credQ[3 * HD + tid];
        }
    }
}

// ---------------- reduce pass-2 BN stats from gconv1 partials ----------------
__global__ __launch_bounds__(256) void k_red2(const float* __restrict__ part2s, const float* __restrict__ part2q,
                                              float* __restrict__ colsum, float* __restrict__ colsq) {
    __shared__ float ws[8];
    const int col = blockIdx.x, t = threadIdx.x;
    float s = 0.f, sq = 0.f;
    #pragma unroll
    for (int k = 0; k < 4; ++k) {
        s  += part2s[(size_t)(t + k * 256) * HD + col];
        sq += part2q[(size_t)(t + k * 256) * HD + col];
    }
    #pragma unroll
    for (int mk = 1; mk <= 32; mk <<= 1) {
        s  += __shfl_xor(s, mk, 64);
        sq += __shfl_xor(sq, mk, 64);
    }
    if ((t & 63) == 0) { ws[(t >> 6) * 2] = s; ws[(t >> 6) * 2 + 1] = sq; }
    __syncthreads();
    if (t == 0) colsum[col] = ws[0] + ws[2] + ws[4] + ws[6];
    if (t == 1) colsq[col]  = ws[1] + ws[3] + ws[5] + ws[7];
}

// ---------------- segment softmax ----------------
__global__ __launch_bounds__(256) void k_segsoftmax(const float* __restrict__ att, float* __restrict__ alpha) {
    const int hh = blockIdx.x >> 6, g = blockIdx.x & 63;
    const int t = threadIdx.x;
    const float* a = att + (size_t)hh * NN + g * NPG;
    float* al = alpha + (size_t)hh * NN + g * NPG;
    float v[4]; float mx = -1e30f;
    #pragma unroll
    for (int i = 0; i < 4; ++i) { v[i] = a[t + i * 256]; mx = fmaxf(mx, v[i]); }
    #pragma unroll
    for (int m = 32; m > 0; m >>= 1) mx = fmaxf(mx, __shfl_xor(mx, m, 64));
    __shared__ float redm[4], reds[4];
    if ((t & 63) == 0) redm[t >> 6] = mx;
    __syncthreads();
    mx = fmaxf(fmaxf(redm[0], redm[1]), fmaxf(redm[2], redm[3]));
    float s = 0.f;
    #pragma unroll
    for (int i = 0; i < 4; ++i) { v[i] = __expf(v[i] - mx); s += v[i]; }
    #pragma unroll
    for (int m = 32; m > 0; m >>= 1) s += __shfl_xor(s, m, 64);
    if ((t & 63) == 0) reds[t >> 6] = s;
    __syncthreads();
    s = reds[0] + reds[1] + reds[2] + reds[3];
    float inv = 1.f / s;
    #pragma unroll
    for (int i = 0; i < 4; ++i) al[t + i * 256] = v[i] * inv;
}

// ---------------- mo + x1 = LN(mo + h2), bf16 in/out ----------------
__global__ __launch_bounds__(256) void k_mo_x1(const unsigned short* __restrict__ h2b,
                                               const unsigned short* __restrict__ Ufrag,
                                               const float* __restrict__ alpha,
                                               const float* __restrict__ lng, const float* __restrict__ lnb,
                                               unsigned short* __restrict__ x1b) {
    const int tid = threadIdx.x;
    const int w = tid >> 6, l = tid & 63, q = l >> 4, m = l & 15;
    const int node = blockIdx.x * BM + w * 16 + m;
    bf16x8s a[4];
    #pragma unroll
    for (int ks = 0; ks < 4; ++ks)
        a[ks] = *(const bf16x8s*)(h2b + (size_t)node * HD + ks * 32 + q * 8);
    f32x4 mo[8] = {};
    #pragma unroll
    for (int hh = 0; hh < 4; ++hh) {
        f32x4 acc[8] = {};
        #pragma unroll
        for (int ks = 0; ks < 4; ++ks) {
            #pragma unroll
            for (int c = 0; c < 8; ++c) {
                bf16x8s b = *(const bf16x8s*)(Ufrag + (size_t)(((hh * 4 + ks) * 8 + c) * 64 + l) * 8);
                acc[c] = MFMA16(b, a[ks], acc[c]);
            }
        }
        float al = alpha[(size_t)hh * NN + node];
        #pragma unroll
        for (int c = 0; c < 8; ++c) {
            mo[c][0] += al * acc[c][0];
            mo[c][1] += al * acc[c][1];
            mo[c][2] += al * acc[c][2];
            mo[c][3] += al * acc[c][3];
        }
    }
    float vals[8][4]; float s = 0.f, sq = 0.f;
    #pragma unroll
    for (int c = 0; c < 8; ++c) {
        const int col = c * 16 + q * 4;
        ushort4 hv = *(const ushort4*)(h2b + (size_t)node * HD + col);
        vals[c][0] = mo[c][0] + b2f(hv.x);
        vals[c][1] = mo[c][1] + b2f(hv.y);
        vals[c][2] = mo[c][2] + b2f(hv.z);
        vals[c][3] = mo[c][3] + b2f(hv.w);
        #pragma unroll
        for (int r = 0; r < 4; ++r) { s += vals[c][r]; sq += vals[c][r] * vals[c][r]; }
    }
    s  += __shfl_xor(s, 16, 64);  s  += __shfl_xor(s, 32, 64);
    sq += __shfl_xor(sq, 16, 64); sq += __shfl_xor(sq, 32, 64);
    float mean = s * (1.f / HD);
    float var  = sq * (1.f / HD) - mean * mean;
    float rstd = rsqrtf(var + BEPS);
    #pragma unroll
    for (int c = 0; c < 8; ++c) {
        const int col = c * 16 + q * 4;
        float4 gv = *(const float4*)(lng + col);
        float4 bv = *(const float4*)(lnb + col);
        ushort4 o;
        o.x = f2bf((vals[c][0] - mean) * rstd * gv.x + bv.x);
        o.y = f2bf((vals[c][1] - mean) * rstd * gv.y + bv.y);
        o.z = f2bf((vals[c][2] - mean) * rstd * gv.z + bv.z);
        o.w = f2bf((vals[c][3] - mean) * rstd * gv.w + bv.w);
        *(ushort4*)(x1b + (size_t)node * HD + col) = o;
    }
}

// ---------------- FFN1: mid = bf16(relu(x1 @ Wf1 + bf1)), bf16 in ----------------
__global__ __launch_bounds__(256) void k_ffn1_mfma(const unsigned short* __restrict__ x1b,
                                                   const unsigned short* __restrict__ Wfrag,
                                                   const float* __restrict__ bias,
                                                   unsigned short* __restrict__ mid) {
    const int tid = threadIdx.x;
    const int w = tid >> 6, l = tid & 63, q = l >> 4, m = l & 15;
    const int node = blockIdx.x * BM + w * 16 + m;
    bf16x8s a[4];
    #pragma unroll
    for (int ks = 0; ks < 4; ++ks)
        a[ks] = *(const bf16x8s*)(x1b + (size_t)node * HD + ks * 32 + q * 8);
    f32x4 acc[16] = {};
    #pragma unroll
    for (int ks = 0; ks < 4; ++ks) {
        #pragma unroll
        for (int c = 0; c < 16; ++c) {
            bf16x8s b = *(const bf16x8s*)(Wfrag + (size_t)((ks * 16 + c) * 64 + l) * 8);
            acc[c] = MFMA16(b, a[ks], acc[c]);
        }
    }
    #pragma unroll
    for (int c = 0; c < 16; ++c) {
        const int col = c * 16 + q * 4;
        float4 bv = *(const float4*)(bias + col);
        ushort4 o;
        o.x = f2bf(fmaxf(acc[c][0] + bv.x, 0.f));
        o.y = f2bf(fmaxf(acc[c][1] + bv.y, 0.f));
        o.z = f2bf(fmaxf(acc[c][2] + bv.z, 0.f));
        o.w = f2bf(fmaxf(acc[c][3] + bv.w, 0.f));
        *(ushort4*)(mid + (size_t)node * HD2 + col) = o;
    }
}

// ---------------- FFN2 + LN + readout partials (non-atomic) ----------------
__global__ __launch_bounds__(256) void k_ffn2_mfma(const unsigned short* __restrict__ mid,
                                                   const unsigned short* __restrict__ Wfrag,
                                                   const float* __restrict__ bias,
                                                   const unsigned short* __restrict__ x1b,
                                                   const float* __restrict__ lng, const float* __restrict__ lnb,
                                                   float* __restrict__ rpart) {
    __shared__ float cred[4 * HD];
    const int tid = threadIdx.x;
    const int w = tid >> 6, l = tid & 63, q = l >> 4, m = l & 15;
    const int node = blockIdx.x * BM + w * 16 + m;
    bf16x8s a[8];
    #pragma unroll
    for (int ks = 0; ks < 8; ++ks)
        a[ks] = *(const bf16x8s*)(mid + (size_t)node * HD2 + ks * 32 + q * 8);
    f32x4 acc[8] = {};
    #pragma unroll
    for (int ks = 0; ks < 8; ++ks) {
        #pragma unroll
        for (int c = 0; c < 8; ++c) {
            bf16x8s b = *(const bf16x8s*)(Wfrag + (size_t)((ks * 8 + c) * 64 + l) * 8);
            acc[c] = MFMA16(b, a[ks], acc[c]);
        }
    }
    float vals[8][4]; float s = 0.f, sq = 0.f;
    #pragma unroll
    for (int c = 0; c < 8; ++c) {
        const int col = c * 16 + q * 4;
        float4 bv = *(const float4*)(bias + col);
        ushort4 xv = *(const ushort4*)(x1b + (size_t)node * HD + col);
        vals[c][0] = acc[c][0] + bv.x + b2f(xv.x);
        vals[c][1] = acc[c][1] + bv.y + b2f(xv.y);
        vals[c][2] = acc[c][2] + bv.z + b2f(xv.z);
        vals[c][3] = acc[c][3] + bv.w + b2f(xv.w);
        #pragma unroll
        for (int r = 0; r < 4; ++r) { s += vals[c][r]; sq += vals[c][r] * vals[c][r]; }
    }
    s  += __shfl_xor(s, 16, 64);  s  += __shfl_xor(s, 32, 64);
    sq += __shfl_xor(sq, 16, 64); sq += __shfl_xor(sq, 32, 64);
    float mean = s * (1.f / HD);
    float var  = sq * (1.f / HD) - mean * mean;
    float rstd = rsqrtf(var + BEPS);
    #pragma unroll
    for (int c = 0; c < 8; ++c) {
        const int col = c * 16 + q * 4;
        float4 gv = *(const float4*)(lng + col);
        float4 bv = *(const float4*)(lnb + col);
        float4 o;
        o.x = (vals[c][0] - mean) * rstd * gv.x + bv.x;
        o.y = (vals[c][1] - mean) * rstd * gv.y + bv.y;
        o.z = (vals[c][2] - mean) * rstd * gv.z + bv.z;
        o.w = (vals[c][3] - mean) * rstd * gv.w + bv.w;
        #pragma unroll
        for (int mk = 1; mk <= 8; mk <<= 1) {
            o.x += __shfl_xor(o.x, mk, 64);
            o.y += __shfl_xor(o.y, mk, 64);
            o.z += __shfl_xor(o.z, mk, 64);
            o.w += __shfl_xor(o.w, mk, 64);
        }
        if (m == 0) *(float4*)(cred + w * HD + col) = o;
    }
    __syncthreads();
    if (tid < HD)
        rpart[(size_t)blockIdx.x * HD + tid] =
            cred[tid] + cred[HD + tid] + cred[2 * HD + tid] + cred[3 * HD + tid];
}

// ---------------- final readout reduce: out[g][c] = sum of 16 block partials ----------------
__global__ __launch_bounds__(256) void k_redout(const float* __restrict__ rpart, float* __restrict__ outp) {
    __shared__ float ls[256];
    const int g = blockIdx.x, t = threadIdx.x;
    const int c = t & 127, half = t >> 7;
    float s = 0.f;
    #pragma unroll
    for (int k = 0; k < 8; ++k)
        s += rpart[(size_t)(g * 16 + half * 8 + k) * HD + c];
    ls[t] = s;
    __syncthreads();
    if (t < 128) outp[g * HD + t] = ls[t] + ls[t + 128];
}

extern "C" void kernel_launch(void* const* d_in, const int* in_sizes, int n_in,
                              void* d_out, int out_size, void* d_ws, size_t ws_size,
                              hipStream_t stream) {
    (void)in_sizes; (void)n_in; (void)out_size;
    const float* h      = (const float*)d_in[0];
    const float* interf = (const float*)d_in[1];
    const float* gamma1 = (const float*)d_in[2];
    const float* beta1  = (const float*)d_in[3];
    const float* W1     = (const float*)d_in[4];
    const float* b1     = (const float*)d_in[5];
    const float* gamma2 = (const float*)d_in[6];
    const float* beta2  = (const float*)d_in[7];
    const float* W2     = (const float*)d_in[8];
    const float* b2     = (const float*)d_in[9];
    const float* Wq     = (const float*)d_in[10];
    const float* Wk     = (const float*)d_in[11];
    const float* Wv     = (const float*)d_in[12];
    const float* Wc     = (const float*)d_in[13];
    const float* ln_g   = (const float*)d_in[14];
    const float* ln_b   = (const float*)d_in[15];
    const float* Wf1    = (const float*)d_in[16];
    const float* bf1    = (const float*)d_in[17];
    const float* Wf2    = (const float*)d_in[18];
    const float* bf2    = (const float*)d_in[19];
    const int*   src    = (const int*)d_in[20];
    const int*   dst    = (const int*)d_in[21];

    float* out = (float*)d_out;              // [0:8192) readout, [8192:16384) init_avg_h
    float* R1 = (float*)d_ws;                // 32MB: dbuck/sbuck -> h1b(bf16) -> x1b(bf16)
    float* R2 = R1 + 8388608;                // 32MB: elist | (upper: psum/psq/part2/rpart) -> h2b(bf16)
    float* R3 = R2 + 8388608;                // 32MB: xr|aggb|att/alpha -> mid (FULL 32MB)
    float* aux = R3 + 8388608;

    unsigned int*   dbuck = (unsigned int*)R1;               // 64*20480 u32 (dead before h1b)
    unsigned short* sbuck = (unsigned short*)(R1 + 1310720); // 64*20480 u16 (dead before h1b)
    unsigned short* h1b   = (unsigned short*)R1;             // 16MB bf16 (dead after gconv2)
    unsigned short* x1b   = (unsigned short*)R1;             // overlays h1b
    unsigned short* elist = (unsigned short*)R2;             // 64*20480 u16 = 2.6MB (dead before h2b)
    unsigned short* h2b   = (unsigned short*)R2;             // 16MB bf16 (lower half of R2)
    float* rpart  = R2 + 4194304;            // 131072 (written at ffn2)
    float* part2s = R2 + 4325376;            // 131072 (gconv1 -> red2)
    float* part2q = R2 + 4456448;            // 131072
    float* psum   = R2 + 4587520;            // 32768 (prep_pool -> wprep)
    float* psq    = R2 + 4620288;            // 32768
    unsigned short* xr   = (unsigned short*)R3;              // 16MB: xr1 then xr2
    unsigned short* aggb = (unsigned short*)(R3 + 4194304);  // 16MB
    float* att    = R3;                      // overlays xr (dead after agg2)
    float* alpha  = R3 + 262144;
    unsigned short* mid = (unsigned short*)R3;  // FULL 32MB of R3 (att/alpha/aggb dead by ffn1)

    float* dout_r  = aux;                    // 65536
    float* din_r   = aux + 65536;            // 65536
    float* colsum1 = aux + 131072;           // 128
    float* colsq1  = aux + 131200;
    float* colsum2 = aux + 131328;
    float* colsq2  = aux + 131456;
    int*   gcurD   = (int*)(aux + 131584);   // 64 counters, stride-32 padded (2048 ints)
    int*   gcurS   = (int*)(aux + 133632);   // 2048 ints
    float* watt    = aux + 135680;           // 32768 -> 168448
    int*   beg     = (int*)(aux + 168448);   // 65536 -> 233984
    int*   endv    = (int*)(aux + 233984);   // 65536 -> 299520
    float* sd      = aux + 299520;           // 65536 -> 365056
    unsigned short* W1f  = (unsigned short*)(aux + 365056);  // 16384 sh
    unsigned short* W2f  = (unsigned short*)(aux + 373248);
    unsigned short* Wf1f = (unsigned short*)(aux + 381440);  // 32768 sh
    unsigned short* Wf2f = (unsigned short*)(aux + 397824);
    unsigned short* Uf   = (unsigned short*)(aux + 414208);  // 65536 sh -> ends 446976

    if (ws_size < (size_t)(25165824 + 446976) * 4) return;

    hipMemsetAsync(gcurD, 0, 4096 * sizeof(int), stream);   // gcurD+gcurS contiguous

    k_prep_pool<<<320, 1024, 0, stream>>>(src, dst, gcurD, gcurS, dbuck, sbuck, h, psum, psq);
    k_prep2<<<128, 1024, 0, stream>>>(gcurD, gcurS, dbuck, sbuck, din_r, dout_r, beg, endv, elist);
    k_sdpack<<<4352, 256, 0, stream>>>(h, dout_r, xr, beg, endv, elist, sd);
    k_wprep<<<688, 256, 0, stream>>>(W1, W2, Wf1, Wf2, interf, Wk, Wq, Wv, Wc,
                                     W1f, W2f, Wf1f, Wf2f, watt, Uf,
                                     psum, psq, out + 8192, colsum1, colsq1);

    // gconv block 1 (stats partials + xr2 write fused into epilogue)
    k_aggregate<<<16384, 256, 0, stream>>>(xr, din_r, sd, colsum1, colsq1, gamma1, beta1,
                                           beg, endv, elist, aggb);
    k_gconv_mfma<false, true, true, true><<<1024, 256, 0, stream>>>(aggb, W1f, b1, h, h1b,
                                                                    nullptr, nullptr, part2s, part2q,
                                                                    dout_r, xr);
    k_red2<<<128, 256, 0, stream>>>(part2s, part2q, colsum2, colsq2);

    // gconv block 2 (+ fused attention scores)
    k_aggregate<<<16384, 256, 0, stream>>>(xr, din_r, sd, colsum2, colsq2, gamma2, beta2,
                                           beg, endv, elist, aggb);
    k_gconv_mfma<true, false, false, false><<<1024, 256, 0, stream>>>(aggb, W2f, b2, h1b, h2b,
                                                                      watt, att, nullptr, nullptr,
                                                                      nullptr, nullptr);

    // attention softmax + tail (separate high-occupancy kernels)
    k_segsoftmax<<<256, 256, 0, stream>>>(att, alpha);
    k_mo_x1<<<1024, 256, 0, stream>>>(h2b, Uf, alpha, ln_g, ln_b, x1b);
    k_ffn1_mfma<<<1024, 256, 0, stream>>>(x1b, Wf1f, bf1, mid);
    k_ffn2_mfma<<<1024, 256, 0, stream>>>(mid, Wf2f, bf2, x1b, ln_g, ln_b, rpart);
    k_redout<<<64, 256, 0, stream>>>(rpart, out);
}

// Round 15
// 282.308 us; speedup vs baseline: 1.0334x; 1.0334x over previous
//
#include <hip/hip_runtime.h>

#define NN 65536
#define NE 1048576
#define NB 64
#define HD 128
#define HD2 256
#define NHEAD 4
#define NPG 1024
#define BEPS 1e-5f
#define BM 64
#define ESTRIDE 20480   // per-graph edge bucket stride (mean 16384, +32 sigma)

typedef short bf16x8s __attribute__((ext_vector_type(8)));
typedef float f32x4 __attribute__((ext_vector_type(4)));
#define MFMA16(a,b,c) __builtin_amdgcn_mfma_f32_16x16x32_bf16(a,b,c,0,0,0)

__device__ __forceinline__ unsigned short f2bf(float f) {
    union { float f; unsigned int u; } x{f};
    unsigned int r = x.u + 0x7FFFu + ((x.u >> 16) & 1u);
    return (unsigned short)(r >> 16);
}
__device__ __forceinline__ float b2f(unsigned short s) {
    union { unsigned int u; float f; } x{((unsigned int)s) << 16};
    return x.f;
}

// ---------------- prep pass 1: bucket edges by graph + pool partials ----------------
__global__ __launch_bounds__(1024) void k_prep_pool(const int* __restrict__ src, const int* __restrict__ dst,
                                                    int* __restrict__ gcurD, int* __restrict__ gcurS,
                                                    unsigned int* __restrict__ dbuck, unsigned short* __restrict__ sbuck,
                                                    const float* __restrict__ h,
                                                    float* __restrict__ psum, float* __restrict__ psq) {
    const int t = threadIdx.x;
    if (blockIdx.x < 64) {
        __shared__ int cntD[64], cntS[64], baseD[64], baseS[64];
        if (t < 64) { cntD[t] = 0; cntS[t] = 0; }
        __syncthreads();
        const int e0 = blockIdx.x * 16384;
        int sv[16], dv[16];
        #pragma unroll
        for (int j = 0; j < 16; ++j) {
            int e = e0 + j * 1024 + t;
            sv[j] = src[e]; dv[j] = dst[e];
            atomicAdd(&cntD[dv[j] >> 10], 1);
            atomicAdd(&cntS[sv[j] >> 10], 1);
        }
        __syncthreads();
        if (t < 64) baseD[t] = atomicAdd(&gcurD[t * 32], cntD[t]);
        else if (t < 128) baseS[t - 64] = atomicAdd(&gcurS[(t - 64) * 32], cntS[t - 64]);
        __syncthreads();
        if (t < 64) { cntD[t] = 0; cntS[t] = 0; }
        __syncthreads();
        #pragma unroll
        for (int j = 0; j < 16; ++j) {
            int gd = dv[j] >> 10;
            int slot = baseD[gd] + atomicAdd(&cntD[gd], 1);
            if (slot < ESTRIDE)
                dbuck[gd * ESTRIDE + slot] = (unsigned)(dv[j] & 1023) | ((unsigned)sv[j] << 10);
            int gs = sv[j] >> 10;
            int slot2 = baseS[gs] + atomicAdd(&cntS[gs], 1);
            if (slot2 < ESTRIDE)
                sbuck[gs * ESTRIDE + slot2] = (unsigned short)(sv[j] & 1023);
        }
    } else {
        __shared__ float ls[1024], lq[1024];
        const int bb = blockIdx.x - 64;     // 256 strips of 256 rows
        const int r0 = bb * 256;
        const int c = t & 127, strip8 = t >> 7;
        float s = 0.f, sq = 0.f;
        for (int i = 0; i < 32; ++i) {
            float v = h[(size_t)(r0 + strip8 * 32 + i) * HD + c];
            s += v; sq += v * v;
        }
        ls[t] = s; lq[t] = sq;
        __syncthreads();
        if (t < 128) {
            float ss = 0.f, qq = 0.f;
            #pragma unroll
            for (int k = 0; k < 8; ++k) { ss += ls[t + k * 128]; qq += lq[t + k * 128]; }
            psum[bb * HD + t] = ss;
            psq[bb * HD + t]  = qq;
        }
    }
}

// ---------------- prep pass 2: per-graph CSR build (u16 elist) + degrees ----------------
__global__ __launch_bounds__(1024) void k_prep2(const int* __restrict__ gcurD, const int* __restrict__ gcurS,
                                                const unsigned int* __restrict__ dbuck,
                                                const unsigned short* __restrict__ sbuck,
                                                float* __restrict__ din_r, float* __restrict__ dout_r,
                                                int* __restrict__ beg, int* __restrict__ endv,
                                                unsigned short* __restrict__ elist) {
    __shared__ int hist[1024];
    __shared__ int pre[1024];
    const int t = threadIdx.x;
    const int b = blockIdx.x;
    if (b < 64) {
        const int g = b;
        const int n = min(gcurD[g * 32], ESTRIDE);
        const unsigned int* pd = dbuck + g * ESTRIDE;
        hist[t] = 0;
        __syncthreads();
        for (int i = t; i < n; i += 1024) atomicAdd(&hist[pd[i] & 1023], 1);
        __syncthreads();
        const int cnt = hist[t];
        din_r[g * 1024 + t] = rsqrtf((float)max(cnt, 1));
        int x = cnt; pre[t] = x;
        __syncthreads();
        #pragma unroll
        for (int off = 1; off < 1024; off <<= 1) {
            int v = (t >= off) ? pre[t - off] : 0;
            __syncthreads();
            x += v; pre[t] = x;
            __syncthreads();
        }
        const int excl = x - cnt;
        beg[g * 1024 + t]  = g * ESTRIDE + excl;
        endv[g * 1024 + t] = g * ESTRIDE + excl + cnt;
        __syncthreads();
        hist[t] = excl; pre[t] = 0;
        __syncthreads();
        for (int i = t; i < n; i += 1024) {
            unsigned int w = pd[i];
            int dl = w & 1023;
            int r = atomicAdd(&pre[dl], 1);
            elist[g * ESTRIDE + hist[dl] + r] = (unsigned short)(w >> 10);   // src fits u16
        }
    } else {
        const int g = b - 64;
        const int m = min(gcurS[g * 32], ESTRIDE);
        const unsigned short* ps = sbuck + g * ESTRIDE;
        hist[t] = 0;
        __syncthreads();
        for (int i = t; i < m; i += 1024) atomicAdd(&hist[ps[i]], 1);
        __syncthreads();
        dout_r[g * 1024 + t] = rsqrtf((float)max(hist[t], 1));
    }
}

// ---------------- fused weight prep + pass-1 stats reduce + init_avg + pack + sd ----------------
__device__ __forceinline__ void dev_prepW(int idx, const float* __restrict__ W,
                                          unsigned short* __restrict__ frag, int O) {
    int l = idx & 63, tt = idx >> 6;
    int ot = O >> 4;
    int c = tt % ot, ks = tt / ot;
    int q = l >> 4, m = l & 15;
    const float* wp = W + (size_t)(ks * 32 + q * 8) * O + c * 16 + m;
    union { uint4 v; unsigned short u[8]; } pk;
    #pragma unroll
    for (int j = 0; j < 8; ++j) pk.u[j] = f2bf(wp[(size_t)j * O]);
    *(uint4*)(frag + (size_t)idx * 8) = pk.v;
}

__global__ __launch_bounds__(256) void k_wprep(const float* __restrict__ W1, const float* __restrict__ W2,
                                               const float* __restrict__ Wf1, const float* __restrict__ Wf2,
                                               const float* __restrict__ interf, const float* __restrict__ Wk,
                                               const float* __restrict__ Wq, const float* __restrict__ Wv,
                                               const float* __restrict__ Wc,
                                               unsigned short* __restrict__ W1f, unsigned short* __restrict__ W2f,
                                               unsigned short* __restrict__ Wf1f, unsigned short* __restrict__ Wf2f,
                                               float* __restrict__ watt, unsigned short* __restrict__ Uf,
                                               const float* __restrict__ psum, const float* __restrict__ psq,
                                               float* __restrict__ out_avg,
                                               float* __restrict__ colsum, float* __restrict__ colsq,
                                               const float* __restrict__ x, const float* __restrict__ dout_r,
                                               unsigned short* __restrict__ xr,
                                               const int* __restrict__ beg, const int* __restrict__ endv,
                                               const unsigned short* __restrict__ elist,
                                               float* __restrict__ sd) {
    const int b = blockIdx.x, t = threadIdx.x;
    if (b < 8)        dev_prepW(b * 256 + t, W1, W1f, 128);
    else if (b < 16)  dev_prepW((b - 8) * 256 + t, W2, W2f, 128);
    else if (b < 32)  dev_prepW((b - 16) * 256 + t, Wf1, Wf1f, 256);
    else if (b < 48)  dev_prepW((b - 32) * 256 + t, Wf2, Wf2f, 128);
    else if (b < 304) {
        int hb = b - 48;                 // h*64+g
        int hh = hb >> 6, g = hb & 63;
        __shared__ float f[HD];
        __shared__ float kv[HD];
        if (t < HD) f[t] = interf[g * HD + t];
        __syncthreads();
        if (t < HD) {
            const float* Wkh = Wk + (size_t)hh * HD * HD;
            float s = 0.f;
            for (int d = 0; d < HD; ++d) s += f[d] * Wkh[(size_t)d * HD + t];
            kv[t] = s;
        }
        __syncthreads();
        if (t < HD) {
            const float* row = Wq + ((size_t)hh * HD + t) * HD;
            float s2 = 0.f;
            #pragma unroll 4
            for (int o = 0; o < HD; o += 4) {
                float4 w = *(const float4*)(row + o);
                s2 += w.x * kv[o] + w.y * kv[o + 1] + w.z * kv[o + 2] + w.w * kv[o + 3];
            }
            watt[hb * HD + t] = s2 * 0.027950849718747373f;   // 1/sqrt(1280)
        }
    } else if (b < 560) {
        int idx = (b - 304) * 256 + t;   // 65536 total
        int o = idx & 127;
        int d = (idx >> 7) & 127;
        int hh = idx >> 14;
        const float* wv = Wv + ((size_t)hh * HD + d) * HD;
        const float* wc = Wc + (size_t)(hh * HD) * HD + o;
        float s = 0.f;
        for (int m2 = 0; m2 < HD; ++m2) s += wv[m2] * wc[(size_t)m2 * HD];
        int ks = d >> 5, dd = d & 31, q = dd >> 3, j = dd & 7;
        int c = o >> 4, m = o & 15, l = q * 16 + m;
        Uf[(size_t)((((hh * 4 + ks) * 8 + c) * 64 + l) * 8 + j)] = f2bf(s);
    } else if (b < 688) {
        // pass-1 BN stats + init mean pooling from non-atomic partials
        const int col = b - 560;         // 128 blocks, one column each
        __shared__ float ls[256], lq[256];
        ls[t] = psum[t * HD + col];
        lq[t] = psq[t * HD + col];
        __syncthreads();
        if (t < 64) {
            float a4 = ls[4 * t] + ls[4 * t + 1] + ls[4 * t + 2] + ls[4 * t + 3];
            out_avg[t * HD + col] = a4 * (1.0f / NPG);
            float b4 = lq[4 * t] + lq[4 * t + 1] + lq[4 * t + 2] + lq[4 * t + 3];
            float ts = a4, tq = b4;
            #pragma unroll
            for (int mk = 1; mk <= 32; mk <<= 1) {
                ts += __shfl_xor(ts, mk, 64);
                tq += __shfl_xor(tq, mk, 64);
            }
            if (t == 0) { colsum[col] = ts; colsq[col] = tq; }
        }
    } else if (b < 4784) {
        // pack: xr = bf16(h * dout_r)
        int idx = (b - 688) * 256 + t;   // N*16 threads, 8 elems each
        int node = idx >> 4;
        int c8 = (idx & 15) * 8;
        float dr = dout_r[node];
        float4 v0 = *(const float4*)(x + (size_t)node * HD + c8);
        float4 v1 = *(const float4*)(x + (size_t)node * HD + c8 + 4);
        union { uint4 v; unsigned short u[8]; } pk;
        pk.u[0] = f2bf(v0.x * dr); pk.u[1] = f2bf(v0.y * dr);
        pk.u[2] = f2bf(v0.z * dr); pk.u[3] = f2bf(v0.w * dr);
        pk.u[4] = f2bf(v1.x * dr); pk.u[5] = f2bf(v1.y * dr);
        pk.u[6] = f2bf(v1.z * dr); pk.u[7] = f2bf(v1.w * dr);
        *(uint4*)(xr + (size_t)node * HD + c8) = pk.v;
    } else {
        // sd[d] = sum dout_r[src]
        const int node = (b - 4784) * 256 + t;
        const int b0 = beg[node], e0 = endv[node];
        float s = 0.f;
        for (int i = b0; i < e0; ++i) s += dout_r[elist[i]];
        sd[node] = s;
    }
}

// ---------------- CSR aggregation: 2 nodes per wave (MLP), BN affine in epilogue ----------------
// agg_bn[d][c] = din[d] * ( sc[c]*sum(xr[s][c]) + sh[c]*sd[d] ),  xr = bf16(x*dout_r)
__global__ __launch_bounds__(256) void k_aggregate(const unsigned short* __restrict__ xr,
                                                   const float* __restrict__ din_r, const float* __restrict__ sd,
                                                   const float* __restrict__ colsum, const float* __restrict__ colsq,
                                                   const float* __restrict__ gma, const float* __restrict__ bta,
                                                   const int* __restrict__ beg, const int* __restrict__ endv,
                                                   const unsigned short* __restrict__ elist,
                                                   unsigned short* __restrict__ agg) {
    const int tid = threadIdx.x;
    const int nA = blockIdx.x * 8 + (tid >> 6) * 2;
    const int nB = nA + 1;
    const int c2 = (tid & 63) * 2;
    // BN constants for this lane's two columns
    float m0 = colsum[c2] * (1.0f / NN),     m1 = colsum[c2 + 1] * (1.0f / NN);
    float r0 = rsqrtf(colsq[c2] * (1.0f / NN) - m0 * m0 + BEPS);
    float r1 = rsqrtf(colsq[c2 + 1] * (1.0f / NN) - m1 * m1 + BEPS);
    float sc0 = r0 * gma[c2], sc1 = r1 * gma[c2 + 1];
    float sh0 = bta[c2] - m0 * sc0, sh1 = bta[c2 + 1] - m1 * sc1;

    int iA = beg[nA]; const int eA = endv[nA];
    int iB = beg[nB]; const int eB = endv[nB];
    float a0 = 0.f, a1 = 0.f, b0 = 0.f, b1 = 0.f;
    while (iA + 4 <= eA && iB + 4 <= eB) {
        int sA0 = elist[iA], sA1 = elist[iA + 1], sA2 = elist[iA + 2], sA3 = elist[iA + 3];
        int sB0 = elist[iB], sB1 = elist[iB + 1], sB2 = elist[iB + 2], sB3 = elist[iB + 3];
        unsigned int vA0 = *(const unsigned int*)(xr + (size_t)sA0 * HD + c2);
        unsigned int vB0 = *(const unsigned int*)(xr + (size_t)sB0 * HD + c2);
        unsigned int vA1 = *(const unsigned int*)(xr + (size_t)sA1 * HD + c2);
        unsigned int vB1 = *(const unsigned int*)(xr + (size_t)sB1 * HD + c2);
        unsigned int vA2 = *(const unsigned int*)(xr + (size_t)sA2 * HD + c2);
        unsigned int vB2 = *(const unsigned int*)(xr + (size_t)sB2 * HD + c2);
        unsigned int vA3 = *(const unsigned int*)(xr + (size_t)sA3 * HD + c2);
        unsigned int vB3 = *(const unsigned int*)(xr + (size_t)sB3 * HD + c2);
        a0 += b2f((unsigned short)vA0) + b2f((unsigned short)vA1) + b2f((unsigned short)vA2) + b2f((unsigned short)vA3);
        a1 += b2f((unsigned short)(vA0 >> 16)) + b2f((unsigned short)(vA1 >> 16))
            + b2f((unsigned short)(vA2 >> 16)) + b2f((unsigned short)(vA3 >> 16));
        b0 += b2f((unsigned short)vB0) + b2f((unsigned short)vB1) + b2f((unsigned short)vB2) + b2f((unsigned short)vB3);
        b1 += b2f((unsigned short)(vB0 >> 16)) + b2f((unsigned short)(vB1 >> 16))
            + b2f((unsigned short)(vB2 >> 16)) + b2f((unsigned short)(vB3 >> 16));
        iA += 4; iB += 4;
    }
    for (; iA + 4 <= eA; iA += 4) {
        int s0 = elist[iA], s1 = elist[iA + 1], s2 = elist[iA + 2], s3 = elist[iA + 3];
        unsigned int v0 = *(const unsigned int*)(xr + (size_t)s0 * HD + c2);
        unsigned int v1 = *(const unsigned int*)(xr + (size_t)s1 * HD + c2);
        unsigned int v2 = *(const unsigned int*)(xr + (size_t)s2 * HD + c2);
        unsigned int v3 = *(const unsigned int*)(xr + (size_t)s3 * HD + c2);
        a0 += b2f((unsigned short)v0) + b2f((unsigned short)v1) + b2f((unsigned short)v2) + b2f((unsigned short)v3);
        a1 += b2f((unsigned short)(v0 >> 16)) + b2f((unsigned short)(v1 >> 16))
            + b2f((unsigned short)(v2 >> 16)) + b2f((unsigned short)(v3 >> 16));
    }
    for (; iA < eA; ++iA) {
        unsigned int v = *(const unsigned int*)(xr + (size_t)elist[iA] * HD + c2);
        a0 += b2f((unsigned short)v); a1 += b2f((unsigned short)(v >> 16));
    }
    for (; iB + 4 <= eB; iB += 4) {
        int s0 = elist[iB], s1 = elist[iB + 1], s2 = elist[iB + 2], s3 = elist[iB + 3];
        unsigned int v0 = *(const unsigned int*)(xr + (size_t)s0 * HD + c2);
        unsigned int v1 = *(const unsigned int*)(xr + (size_t)s1 * HD + c2);
        unsigned int v2 = *(const unsigned int*)(xr + (size_t)s2 * HD + c2);
        unsigned int v3 = *(const unsigned int*)(xr + (size_t)s3 * HD + c2);
        b0 += b2f((unsigned short)v0) + b2f((unsigned short)v1) + b2f((unsigned short)v2) + b2f((unsigned short)v3);
        b1 += b2f((unsigned short)(v0 >> 16)) + b2f((unsigned short)(v1 >> 16))
            + b2f((unsigned short)(v2 >> 16)) + b2f((unsigned short)(v3 >> 16));
    }
    for (; iB < eB; ++iB) {
        unsigned int v = *(const unsigned int*)(xr + (size_t)elist[iB] * HD + c2);
        b0 += b2f((unsigned short)v); b1 += b2f((unsigned short)(v >> 16));
    }
    {
        float dn = din_r[nA], sv = sd[nA];
        ushort2 o;
        o.x = f2bf(dn * (a0 * sc0 + sh0 * sv));
        o.y = f2bf(dn * (a1 * sc1 + sh1 * sv));
        *(ushort2*)(agg + (size_t)nA * HD + c2) = o;
    }
    {
        float dn = din_r[nB], sv = sd[nB];
        ushort2 o;
        o.x = f2bf(dn * (b0 * sc0 + sh0 * sv));
        o.y = f2bf(dn * (b1 * sc1 + sh1 * sv));
        *(ushort2*)(agg + (size_t)nB * HD + c2) = o;
    }
}

// ---------------- gconv MFMA: out(bf16) = res + relu(agg @ W + b); fused scores / stats / xr write ----------------
template<bool SCORES, bool STATS, bool RES32, bool WXR>
__global__ __launch_bounds__(256) void k_gconv_mfma(const unsigned short* __restrict__ agg,
                                                    const unsigned short* __restrict__ Wfrag,
                                                    const float* __restrict__ bias,
                                                    const void* __restrict__ res, unsigned short* __restrict__ outp,
                                                    const float* __restrict__ watt, float* __restrict__ att,
                                                    float* __restrict__ part2s, float* __restrict__ part2q,
                                                    const float* __restrict__ dout_r, unsigned short* __restrict__ xrout) {
    __shared__ float credS[4 * HD];
    __shared__ float credQ[4 * HD];
    const int tid = threadIdx.x;
    const int w = tid >> 6, l = tid & 63, q = l >> 4, m = l & 15;
    const int node = blockIdx.x * BM + w * 16 + m;
    bf16x8s a[4];
    #pragma unroll
    for (int ks = 0; ks < 4; ++ks)
        a[ks] = *(const bf16x8s*)(agg + (size_t)node * HD + ks * 32 + q * 8);
    f32x4 acc[8] = {};
    #pragma unroll
    for (int ks = 0; ks < 4; ++ks) {
        #pragma unroll
        for (int c = 0; c < 8; ++c) {
            bf16x8s b = *(const bf16x8s*)(Wfrag + (size_t)((ks * 8 + c) * 64 + l) * 8);
            acc[c] = MFMA16(b, a[ks], acc[c]);
        }
    }
    float vals[8][4];
    float drv = WXR ? dout_r[node] : 0.f;
    #pragma unroll
    for (int c = 0; c < 8; ++c) {
        const int col = c * 16 + q * 4;
        float4 bv = *(const float4*)(bias + col);
        float rv[4];
        if (RES32) {
            float4 r4 = *(const float4*)((const float*)res + (size_t)node * HD + col);
            rv[0] = r4.x; rv[1] = r4.y; rv[2] = r4.z; rv[3] = r4.w;
        } else {
            ushort4 r4 = *(const ushort4*)((const unsigned short*)res + (size_t)node * HD + col);
            rv[0] = b2f(r4.x); rv[1] = b2f(r4.y); rv[2] = b2f(r4.z); rv[3] = b2f(r4.w);
        }
        vals[c][0] = rv[0] + fmaxf(acc[c][0] + bv.x, 0.f);
        vals[c][1] = rv[1] + fmaxf(acc[c][1] + bv.y, 0.f);
        vals[c][2] = rv[2] + fmaxf(acc[c][2] + bv.z, 0.f);
        vals[c][3] = rv[3] + fmaxf(acc[c][3] + bv.w, 0.f);
        ushort4 o;
        o.x = f2bf(vals[c][0]); o.y = f2bf(vals[c][1]);
        o.z = f2bf(vals[c][2]); o.w = f2bf(vals[c][3]);
        *(ushort4*)(outp + (size_t)node * HD + col) = o;
        if (WXR) {
            ushort4 o2;
            o2.x = f2bf(vals[c][0] * drv); o2.y = f2bf(vals[c][1] * drv);
            o2.z = f2bf(vals[c][2] * drv); o2.w = f2bf(vals[c][3] * drv);
            *(ushort4*)(xrout + (size_t)node * HD + col) = o2;
        }
    }
    if (SCORES) {
        const int g = node >> 10;
        #pragma unroll
        for (int hh = 0; hh < NHEAD; ++hh) {
            const float* wp = watt + ((size_t)(hh * NB + g)) * HD;
            float s = 0.f;
            #pragma unroll
            for (int c = 0; c < 8; ++c) {
                const int col = c * 16 + q * 4;
                float4 wv = *(const float4*)(wp + col);
                s += vals[c][0] * wv.x + vals[c][1] * wv.y + vals[c][2] * wv.z + vals[c][3] * wv.w;
            }
            s += __shfl_xor(s, 16, 64);
            s += __shfl_xor(s, 32, 64);
            if (q == 0) att[(size_t)hh * NN + node] = s;
        }
    }
    if (STATS) {
        #pragma unroll
        for (int c = 0; c < 8; ++c) {
            #pragma unroll
            for (int r = 0; r < 4; ++r) {
                float v = vals[c][r];
                float vq = v * v;
                #pragma unroll
                for (int mk = 1; mk <= 8; mk <<= 1) {
                    v  += __shfl_xor(v, mk, 64);
                    vq += __shfl_xor(vq, mk, 64);
                }
                if (m == 0) {
                    credS[w * HD + c * 16 + q * 4 + r] = v;
                    credQ[w * HD + c * 16 + q * 4 + r] = vq;
                }
            }
        }
        __syncthreads();
        if (tid < HD) {
            part2s[(size_t)blockIdx.x * HD + tid] =
                credS[tid] + credS[HD + tid] + credS[2 * HD + tid] + credS[3 * HD + tid];
            part2q[(size_t)blockIdx.x * HD + tid] =
                credQ[tid] + credQ[HD + tid] + credQ[2 * HD + tid] + credQ[3 * HD + tid];
        }
    }
}

// ---------------- reduce pass-2 BN stats from gconv1 partials ----------------
__global__ __launch_bounds__(256) void k_red2(const float* __restrict__ part2s, const float* __restrict__ part2q,
                                              float* __restrict__ colsum, float* __restrict__ colsq) {
    __shared__ float ws[8];
    const int col = blockIdx.x, t = threadIdx.x;
    float s = 0.f, sq = 0.f;
    #pragma unroll
    for (int k = 0; k < 4; ++k) {
        s  += part2s[(size_t)(t + k * 256) * HD + col];
        sq += part2q[(size_t)(t + k * 256) * HD + col];
    }
    #pragma unroll
    for (int mk = 1; mk <= 32; mk <<= 1) {
        s  += __shfl_xor(s, mk, 64);
        sq += __shfl_xor(sq, mk, 64);
    }
    if ((t & 63) == 0) { ws[(t >> 6) * 2] = s; ws[(t >> 6) * 2 + 1] = sq; }
    __syncthreads();
    if (t == 0) colsum[col] = ws[0] + ws[2] + ws[4] + ws[6];
    if (t == 1) colsq[col]  = ws[1] + ws[3] + ws[5] + ws[7];
}

// ---------------- segment softmax ----------------
__global__ __launch_bounds__(256) void k_segsoftmax(const float* __restrict__ att, float* __restrict__ alpha) {
    const int hh = blockIdx.x >> 6, g = blockIdx.x & 63;
    const int t = threadIdx.x;
    const float* a = att + (size_t)hh * NN + g * NPG;
    float* al = alpha + (size_t)hh * NN + g * NPG;
    float v[4]; float mx = -1e30f;
    #pragma unroll
    for (int i = 0; i < 4; ++i) { v[i] = a[t + i * 256]; mx = fmaxf(mx, v[i]); }
    #pragma unroll
    for (int m = 32; m > 0; m >>= 1) mx = fmaxf(mx, __shfl_xor(mx, m, 64));
    __shared__ float redm[4], reds[4];
    if ((t & 63) == 0) redm[t >> 6] = mx;
    __syncthreads();
    mx = fmaxf(fmaxf(redm[0], redm[1]), fmaxf(redm[2], redm[3]));
    float s = 0.f;
    #pragma unroll
    for (int i = 0; i < 4; ++i) { v[i] = __expf(v[i] - mx); s += v[i]; }
    #pragma unroll
    for (int m = 32; m > 0; m >>= 1) s += __shfl_xor(s, m, 64);
    if ((t & 63) == 0) reds[t >> 6] = s;
    __syncthreads();
    s = reds[0] + reds[1] + reds[2] + reds[3];
    float inv = 1.f / s;
    #pragma unroll
    for (int i = 0; i < 4; ++i) al[t + i * 256] = v[i] * inv;
}

// ---------------- mo + x1 = LN(mo + h2), bf16 in/out ----------------
__global__ __launch_bounds__(256) void k_mo_x1(const unsigned short* __restrict__ h2b,
                                               const unsigned short* __restrict__ Ufrag,
                                               const float* __restrict__ alpha,
                                               const float* __restrict__ lng, const float* __restrict__ lnb,
                                               unsigned short* __restrict__ x1b) {
    const int tid = threadIdx.x;
    const int w = tid >> 6, l = tid & 63, q = l >> 4, m = l & 15;
    const int node = blockIdx.x * BM + w * 16 + m;
    bf16x8s a[4];
    #pragma unroll
    for (int ks = 0; ks < 4; ++ks)
        a[ks] = *(const bf16x8s*)(h2b + (size_t)node * HD + ks * 32 + q * 8);
    f32x4 mo[8] = {};
    #pragma unroll
    for (int hh = 0; hh < 4; ++hh) {
        f32x4 acc[8] = {};
        #pragma unroll
        for (int ks = 0; ks < 4; ++ks) {
            #pragma unroll
            for (int c = 0; c < 8; ++c) {
                bf16x8s b = *(const bf16x8s*)(Ufrag + (size_t)(((hh * 4 + ks) * 8 + c) * 64 + l) * 8);
                acc[c] = MFMA16(b, a[ks], acc[c]);
            }
        }
        float al = alpha[(size_t)hh * NN + node];
        #pragma unroll
        for (int c = 0; c < 8; ++c) {
            mo[c][0] += al * acc[c][0];
            mo[c][1] += al * acc[c][1];
            mo[c][2] += al * acc[c][2];
            mo[c][3] += al * acc[c][3];
        }
    }
    float vals[8][4]; float s = 0.f, sq = 0.f;
    #pragma unroll
    for (int c = 0; c < 8; ++c) {
        const int col = c * 16 + q * 4;
        ushort4 hv = *(const ushort4*)(h2b + (size_t)node * HD + col);
        vals[c][0] = mo[c][0] + b2f(hv.x);
        vals[c][1] = mo[c][1] + b2f(hv.y);
        vals[c][2] = mo[c][2] + b2f(hv.z);
        vals[c][3] = mo[c][3] + b2f(hv.w);
        #pragma unroll
        for (int r = 0; r < 4; ++r) { s += vals[c][r]; sq += vals[c][r] * vals[c][r]; }
    }
    s  += __shfl_xor(s, 16, 64);  s  += __shfl_xor(s, 32, 64);
    sq += __shfl_xor(sq, 16, 64); sq += __shfl_xor(sq, 32, 64);
    float mean = s * (1.f / HD);
    float var  = sq * (1.f / HD) - mean * mean;
    float rstd = rsqrtf(var + BEPS);
    #pragma unroll
    for (int c = 0; c < 8; ++c) {
        const int col = c * 16 + q * 4;
        float4 gv = *(const float4*)(lng + col);
        float4 bv = *(const float4*)(lnb + col);
        ushort4 o;
        o.x = f2bf((vals[c][0] - mean) * rstd * gv.x + bv.x);
        o.y = f2bf((vals[c][1] - mean) * rstd * gv.y + bv.y);
        o.z = f2bf((vals[c][2] - mean) * rstd * gv.z + bv.z);
        o.w = f2bf((vals[c][3] - mean) * rstd * gv.w + bv.w);
        *(ushort4*)(x1b + (size_t)node * HD + col) = o;
    }
}

// ---------------- FFN1: mid = bf16(relu(x1 @ Wf1 + bf1)), bf16 in ----------------
__global__ __launch_bounds__(256) void k_ffn1_mfma(const unsigned short* __restrict__ x1b,
                                                   const unsigned short* __restrict__ Wfrag,
                                                   const float* __restrict__ bias,
                                                   unsigned short* __restrict__ mid) {
    const int tid = threadIdx.x;
    const int w = tid >> 6, l = tid & 63, q = l >> 4, m = l & 15;
    const int node = blockIdx.x * BM + w * 16 + m;
    bf16x8s a[4];
    #pragma unroll
    for (int ks = 0; ks < 4; ++ks)
        a[ks] = *(const bf16x8s*)(x1b + (size_t)node * HD + ks * 32 + q * 8);
    f32x4 acc[16] = {};
    #pragma unroll
    for (int ks = 0; ks < 4; ++ks) {
        #pragma unroll
        for (int c = 0; c < 16; ++c) {
            bf16x8s b = *(const bf16x8s*)(Wfrag + (size_t)((ks * 16 + c) * 64 + l) * 8);
            acc[c] = MFMA16(b, a[ks], acc[c]);
        }
    }
    #pragma unroll
    for (int c = 0; c < 16; ++c) {
        const int col = c * 16 + q * 4;
        float4 bv = *(const float4*)(bias + col);
        ushort4 o;
        o.x = f2bf(fmaxf(acc[c][0] + bv.x, 0.f));
        o.y = f2bf(fmaxf(acc[c][1] + bv.y, 0.f));
        o.z = f2bf(fmaxf(acc[c][2] + bv.z, 0.f));
        o.w = f2bf(fmaxf(acc[c][3] + bv.w, 0.f));
        *(ushort4*)(mid + (size_t)node * HD2 + col) = o;
    }
}

// ---------------- FFN2 + LN + readout partials (non-atomic) ----------------
__global__ __launch_bounds__(256) void k_ffn2_mfma(const unsigned short* __restrict__ mid,
                                                   const unsigned short* __restrict__ Wfrag,
                                                   const float* __restrict__ bias,
                                                   const unsigned short* __restrict__ x1b,
                                                   const float* __restrict__ lng, const float* __restrict__ lnb,
                                                   float* __restrict__ rpart) {
    __shared__ float cred[4 * HD];
    const int tid = threadIdx.x;
    const int w = tid >> 6, l = tid & 63, q = l >> 4, m = l & 15;
    const int node = blockIdx.x * BM + w * 16 + m;
    bf16x8s a[8];
    #pragma unroll
    for (int ks = 0; ks < 8; ++ks)
        a[ks] = *(const bf16x8s*)(mid + (size_t)node * HD2 + ks * 32 + q * 8);
    f32x4 acc[8] = {};
    #pragma unroll
    for (int ks = 0; ks < 8; ++ks) {
        #pragma unroll
        for (int c = 0; c < 8; ++c) {
            bf16x8s b = *(const bf16x8s*)(Wfrag + (size_t)((ks * 8 + c) * 64 + l) * 8);
            acc[c] = MFMA16(b, a[ks], acc[c]);
        }
    }
    float vals[8][4]; float s = 0.f, sq = 0.f;
    #pragma unroll
    for (int c = 0; c < 8; ++c) {
        const int col = c * 16 + q * 4;
        float4 bv = *(const float4*)(bias + col);
        ushort4 xv = *(const ushort4*)(x1b + (size_t)node * HD + col);
        vals[c][0] = acc[c][0] + bv.x + b2f(xv.x);
        vals[c][1] = acc[c][1] + bv.y + b2f(xv.y);
        vals[c][2] = acc[c][2] + bv.z + b2f(xv.z);
        vals[c][3] = acc[c][3] + bv.w + b2f(xv.w);
        #pragma unroll
        for (int r = 0; r < 4; ++r) { s += vals[c][r]; sq += vals[c][r] * vals[c][r]; }
    }
    s  += __shfl_xor(s, 16, 64);  s  += __shfl_xor(s, 32, 64);
    sq += __shfl_xor(sq, 16, 64); sq += __shfl_xor(sq, 32, 64);
    float mean = s * (1.f / HD);
    float var  = sq * (1.f / HD) - mean * mean;
    float rstd = rsqrtf(var + BEPS);
    #pragma unroll
    for (int c = 0; c < 8; ++c) {
        const int col = c * 16 + q * 4;
        float4 gv = *(const float4*)(lng + col);
        float4 bv = *(const float4*)(lnb + col);
        float4 o;
        o.x = (vals[c][0] - mean) * rstd * gv.x + bv.x;
        o.y = (vals[c][1] - mean) * rstd * gv.y + bv.y;
        o.z = (vals[c][2] - mean) * rstd * gv.z + bv.z;
        o.w = (vals[c][3] - mean) * rstd * gv.w + bv.w;
        #pragma unroll
        for (int mk = 1; mk <= 8; mk <<= 1) {
            o.x += __shfl_xor(o.x, mk, 64);
            o.y += __shfl_xor(o.y, mk, 64);
            o.z += __shfl_xor(o.z, mk, 64);
            o.w += __shfl_xor(o.w, mk, 64);
        }
        if (m == 0) *(float4*)(cred + w * HD + col) = o;
    }
    __syncthreads();
    if (tid < HD)
        rpart[(size_t)blockIdx.x * HD + tid] =
            cred[tid] + cred[HD + tid] + cred[2 * HD + tid] + cred[3 * HD + tid];
}

// ---------------- final readout reduce: out[g][c] = sum of 16 block partials ----------------
__global__ __launch_bounds__(256) void k_redout(const float* __restrict__ rpart, float* __restrict__ outp) {
    __shared__ float ls[256];
    const int g = blockIdx.x, t = threadIdx.x;
    const int c = t & 127, half = t >> 7;
    float s = 0.f;
    #pragma unroll
    for (int k = 0; k < 8; ++k)
        s += rpart[(size_t)(g * 16 + half * 8 + k) * HD + c];
    ls[t] = s;
    __syncthreads();
    if (t < 128) outp[g * HD + t] = ls[t] + ls[t + 128];
}

extern "C" void kernel_launch(void* const* d_in, const int* in_sizes, int n_in,
                              void* d_out, int out_size, void* d_ws, size_t ws_size,
                              hipStream_t stream) {
    (void)in_sizes; (void)n_in; (void)out_size;
    const float* h      = (const float*)d_in[0];
    const float* interf = (const float*)d_in[1];
    const float* gamma1 = (const float*)d_in[2];
    const float* beta1  = (const float*)d_in[3];
    const float* W1     = (const float*)d_in[4];
    const float* b1     = (const float*)d_in[5];
    const float* gamma2 = (const float*)d_in[6];
    const float* beta2  = (const float*)d_in[7];
    const float* W2     = (const float*)d_in[8];
    const float* b2     = (const float*)d_in[9];
    const float* Wq     = (const float*)d_in[10];
    const float* Wk     = (const float*)d_in[11];
    const float* Wv     = (const float*)d_in[12];
    const float* Wc     = (const float*)d_in[13];
    const float* ln_g   = (const float*)d_in[14];
    const float* ln_b   = (const float*)d_in[15];
    const float* Wf1    = (const float*)d_in[16];
    const float* bf1    = (const float*)d_in[17];
    const float* Wf2    = (const float*)d_in[18];
    const float* bf2    = (const float*)d_in[19];
    const int*   src    = (const int*)d_in[20];
    const int*   dst    = (const int*)d_in[21];

    float* out = (float*)d_out;              // [0:8192) readout, [8192:16384) init_avg_h
    float* R1 = (float*)d_ws;                // 32MB: dbuck/sbuck -> h1b(bf16) -> x1b(bf16)
    float* R2 = R1 + 8388608;                // 32MB: elist | (upper: psum/psq/part2/rpart) -> h2b(bf16)
    float* R3 = R2 + 8388608;                // 32MB: xr|aggb|att/alpha -> mid (FULL 32MB)
    float* aux = R3 + 8388608;

    unsigned int*   dbuck = (unsigned int*)R1;               // 64*20480 u32 (dead before h1b)
    unsigned short* sbuck = (unsigned short*)(R1 + 1310720); // 64*20480 u16 (dead before h1b)
    unsigned short* h1b   = (unsigned short*)R1;             // 16MB bf16 (dead after gconv2)
    unsigned short* x1b   = (unsigned short*)R1;             // overlays h1b
    unsigned short* elist = (unsigned short*)R2;             // 64*20480 u16 = 2.6MB (dead before h2b)
    unsigned short* h2b   = (unsigned short*)R2;             // 16MB bf16 (lower half of R2)
    float* rpart  = R2 + 4194304;            // 131072 (written at ffn2)
    float* part2s = R2 + 4325376;            // 131072 (gconv1 -> red2)
    float* part2q = R2 + 4456448;            // 131072
    float* psum   = R2 + 4587520;            // 32768 (prep_pool -> wprep)
    float* psq    = R2 + 4620288;            // 32768
    unsigned short* xr   = (unsigned short*)R3;              // 16MB: xr1 then xr2
    unsigned short* aggb = (unsigned short*)(R3 + 4194304);  // 16MB
    float* att    = R3;                      // overlays xr (dead after agg2)
    float* alpha  = R3 + 262144;
    unsigned short* mid = (unsigned short*)R3;  // FULL 32MB of R3 (att/alpha/aggb dead by ffn1)

    float* dout_r  = aux;                    // 65536
    float* din_r   = aux + 65536;            // 65536
    float* colsum1 = aux + 131072;           // 128
    float* colsq1  = aux + 131200;
    float* colsum2 = aux + 131328;
    float* colsq2  = aux + 131456;
    int*   gcurD   = (int*)(aux + 131584);   // 64 counters, stride-32 padded (2048 ints)
    int*   gcurS   = (int*)(aux + 133632);   // 2048 ints
    float* watt    = aux + 135680;           // 32768 -> 168448
    int*   beg     = (int*)(aux + 168448);   // 65536 -> 233984
    int*   endv    = (int*)(aux + 233984);   // 65536 -> 299520
    float* sd      = aux + 299520;           // 65536 -> 365056
    unsigned short* W1f  = (unsigned short*)(aux + 365056);  // 16384 sh
    unsigned short* W2f  = (unsigned short*)(aux + 373248);
    unsigned short* Wf1f = (unsigned short*)(aux + 381440);  // 32768 sh
    unsigned short* Wf2f = (unsigned short*)(aux + 397824);
    unsigned short* Uf   = (unsigned short*)(aux + 414208);  // 65536 sh -> ends 446976

    if (ws_size < (size_t)(25165824 + 446976) * 4) return;

    hipMemsetAsync(gcurD, 0, 4096 * sizeof(int), stream);   // gcurD+gcurS contiguous

    k_prep_pool<<<320, 1024, 0, stream>>>(src, dst, gcurD, gcurS, dbuck, sbuck, h, psum, psq);
    k_prep2<<<128, 1024, 0, stream>>>(gcurD, gcurS, dbuck, sbuck, din_r, dout_r, beg, endv, elist);
    k_wprep<<<5040, 256, 0, stream>>>(W1, W2, Wf1, Wf2, interf, Wk, Wq, Wv, Wc,
                                      W1f, W2f, Wf1f, Wf2f, watt, Uf,
                                      psum, psq, out + 8192, colsum1, colsq1,
                                      h, dout_r, xr, beg, endv, elist, sd);

    // gconv block 1 (stats partials + xr2 write fused into epilogue)
    k_aggregate<<<8192, 256, 0, stream>>>(xr, din_r, sd, colsum1, colsq1, gamma1, beta1,
                                          beg, endv, elist, aggb);
    k_gconv_mfma<false, true, true, true><<<1024, 256, 0, stream>>>(aggb, W1f, b1, h, h1b,
                                                                    nullptr, nullptr, part2s, part2q,
                                                                    dout_r, xr);
    k_red2<<<128, 256, 0, stream>>>(part2s, part2q, colsum2, colsq2);

    // gconv block 2 (+ fused attention scores)
    k_aggregate<<<8192, 256, 0, stream>>>(xr, din_r, sd, colsum2, colsq2, gamma2, beta2,
                                          beg, endv, elist, aggb);
    k_gconv_mfma<true, false, false, false><<<1024, 256, 0, stream>>>(aggb, W2f, b2, h1b, h2b,
                                                                      watt, att, nullptr, nullptr,
                                                                      nullptr, nullptr);

    // attention softmax + tail (separate high-occupancy kernels)
    k_segsoftmax<<<256, 256, 0, stream>>>(att, alpha);
    k_mo_x1<<<1024, 256, 0, stream>>>(h2b, Uf, alpha, ln_g, ln_b, x1b);
    k_ffn1_mfma<<<1024, 256, 0, stream>>>(x1b, Wf1f, bf1, mid);
    k_ffn2_mfma<<<1024, 256, 0, stream>>>(mid, Wf2f, bf2, x1b, ln_g, ln_b, rpart);
    k_redout<<<64, 256, 0, stream>>>(rpart, out);
}